// Round 1
// baseline (171.990 us; speedup 1.0000x reference)
//
#include <hip/hip_runtime.h>
#include <hip/hip_bf16.h>
#include <stdint.h>

#define EPSF 1e-5f

typedef short    short8v __attribute__((ext_vector_type(8)));
typedef float    f32x4   __attribute__((ext_vector_type(4)));
typedef uint32_t u32x2   __attribute__((ext_vector_type(2)));
typedef uint32_t u32x4   __attribute__((ext_vector_type(4)));

// dims: T=4, B=16, C=256, H*W=256, Hid=1024, E=8, TOPK=2 -> 32 slots
// x layout (T,B,C,H,W): idx = ((t*16+b)*256+c)*256 + hw ; t-stride = 1048576

static __device__ __forceinline__ short bf16bits(float f) {
    __hip_bfloat16 h = __float2bfloat16(f);
    return *reinterpret_cast<short*>(&h);
}

// ---------------- weight convert: w1 -> hi/lo bf16 split, w2 -> bf16 ----------------
__global__ void k_w(const float* __restrict__ w1, const float* __restrict__ w2,
                    short* __restrict__ w1bf, short* __restrict__ w1lo, short* __restrict__ w2bf) {
    int idx = blockIdx.x * 256 + threadIdx.x;
    if (idx < 2097152) {
        float f = w1[idx];
        __hip_bfloat16 h = __float2bfloat16(f);
        w1bf[idx] = *reinterpret_cast<short*>(&h);
        float hi = __bfloat162float(h);
        w1lo[idx] = bf16bits(f - hi);
        w2bf[idx] = bf16bits(w2[idx]);
    }
}

// ---------------- BN constant folding: scale/shift (conv bias folded in) ----------------
__global__ void k_bn(const float* __restrict__ b1, const float* __restrict__ g1, const float* __restrict__ be1,
                     const float* __restrict__ m1, const float* __restrict__ v1,
                     const float* __restrict__ b2, const float* __restrict__ g2, const float* __restrict__ be2,
                     const float* __restrict__ m2, const float* __restrict__ v2,
                     float* __restrict__ sc1, float* __restrict__ sh1,
                     float* __restrict__ sc2, float* __restrict__ sh2) {
    int idx = blockIdx.x * 256 + threadIdx.x;
    if (idx < 8192) {
        float s = g1[idx] / sqrtf(v1[idx] + EPSF);
        sc1[idx] = s;
        sh1[idx] = be1[idx] + s * (b1[idx] - m1[idx]);
    }
    if (idx < 2048) {
        float s = g2[idx] / sqrtf(v2[idx] + EPSF);
        sc2[idx] = s;
        sh2[idx] = be2[idx] + s * (b2[idx] - m2[idx]);
    }
}

// ---------------- router stage 1: xbar[b][c] = mean over (T,H,W) ----------------
__global__ void k_r1(const float* __restrict__ x, float* __restrict__ xbar) {
    int bc = blockIdx.x;           // b*256 + c
    int lane = threadIdx.x;        // 64
    const float* xp = x + (size_t)bc * 256;
    float s = 0.f;
    #pragma unroll
    for (int t = 0; t < 4; ++t)
        #pragma unroll
        for (int i = 0; i < 4; ++i)
            s += xp[(size_t)t * 1048576 + i * 64 + lane];
    #pragma unroll
    for (int off = 32; off; off >>= 1) s += __shfl_down(s, off);
    if (lane == 0) xbar[bc] = s * (1.0f / 1024.0f);
}

// ---------------- router stage 2: logits -> top-2 -> 32 slots ----------------
__global__ void k_r2(const float* __restrict__ xbar, const float* __restrict__ rw, const float* __restrict__ rb,
                     const float* __restrict__ rg, const float* __restrict__ rbt,
                     const float* __restrict__ rm, const float* __restrict__ rv,
                     int* __restrict__ slotE, float* __restrict__ slotW) {
    __shared__ float L[16][8];
    int tid = threadIdx.x; // 128
    if (tid < 128) {
        int b = tid >> 3, e = tid & 7;
        float s = 0.f;
        for (int c = 0; c < 256; ++c) s += xbar[b * 256 + c] * rw[e * 256 + c];
        s += rb[e];
        L[b][e] = rg[e] * (s - rm[e]) / sqrtf(rv[e] + EPSF) + rbt[e];
    }
    __syncthreads();
    if (tid < 16) {
        int b = tid;
        float l[8];
        #pragma unroll
        for (int e = 0; e < 8; ++e) l[e] = L[b][e];
        int i1 = 0;
        for (int e = 1; e < 8; ++e) if (l[e] > l[i1]) i1 = e;
        int i2 = (i1 == 0) ? 1 : 0;
        for (int e = 0; e < 8; ++e) { if (e == i1) continue; if (l[e] > l[i2]) i2 = e; }
        float d = l[i2] - l[i1];           // <= 0
        float ed = expf(d);
        slotE[b * 2]     = i1; slotW[b * 2]     = 1.f / (1.f + ed);
        slotE[b * 2 + 1] = i2; slotW[b * 2 + 1] = ed / (1.f + ed);
    }
}

// ---------------- LIF1: x -> packed spikes s1p[slot][hw*4+t][8 words of c] ----------------
__global__ void k_lif1(const float* __restrict__ x, const int* __restrict__ slotE,
                       uint32_t* __restrict__ s1p) {
    int slot = blockIdx.x, wq = blockIdx.y;  // wq: which 32-channel word
    int b = slot >> 1, e = slotE[slot];
    float tau = 1.5f + e * (2.5f / 7.0f);
    int hw = threadIdx.x; // 256
    uint32_t wt0 = 0, wt1 = 0, wt2 = 0, wt3 = 0;
    const float* xb = x + ((size_t)b * 256) * 256 + hw;
    for (int j = 0; j < 32; ++j) {
        int c = wq * 32 + j;
        const float* xp = xb + (size_t)c * 256;
        float v = 0.f;
        v = v + (xp[0]       - v) / tau; if (v >= 1.f) { wt0 |= 1u << j; v = 0.f; }
        v = v + (xp[1048576] - v) / tau; if (v >= 1.f) { wt1 |= 1u << j; v = 0.f; }
        v = v + (xp[2097152] - v) / tau; if (v >= 1.f) { wt2 |= 1u << j; v = 0.f; }
        v = v + (xp[3145728] - v) / tau; if (v >= 1.f) { wt3 |= 1u << j; v = 0.f; }
    }
    uint32_t* o = s1p + ((size_t)slot * 1024 + hw * 4) * 8 + wq;
    o[0] = wt0; o[8] = wt1; o[16] = wt2; o[24] = wt3;
}

// ---------------- GEMM1 (spikes x w1 hi/lo) + BN1 + LIF2 -> packed s2p ----------------
// block: M=256 rows (64 tok x 4 t), N=128 hid, K=256 in 8 steps of 32. 512 thr = 8 waves (4m x 2n).
__global__ __launch_bounds__(512) void k_g1(const uint32_t* __restrict__ s1p,
                                            const short* __restrict__ w1bf, const short* __restrict__ w1lo,
                                            const float* __restrict__ sc1, const float* __restrict__ sh1,
                                            const int* __restrict__ slotE, uint32_t* __restrict__ s2p) {
    __shared__ __align__(16) short A[256][40];
    __shared__ __align__(16) short Bh[128][40];
    __shared__ __align__(16) short Bl[128][40];
    __shared__ __align__(16) short LUT[256][8];
    __shared__ unsigned short SPK[256][8];

    const int tid = threadIdx.x;
    const int slot = blockIdx.x, mt = blockIdx.y, nt = blockIdx.z;
    const int e = slotE[slot];

    if (tid < 256) {
        short8v v;
        #pragma unroll
        for (int j = 0; j < 8; ++j) v[j] = ((tid >> j) & 1) ? (short)0x3F80 : (short)0;
        *(short8v*)&LUT[tid][0] = v;
    }

    f32x4 acc[4][4];
    #pragma unroll
    for (int i = 0; i < 4; ++i)
        #pragma unroll
        for (int j = 0; j < 4; ++j) acc[i][j] = (f32x4){0.f, 0.f, 0.f, 0.f};

    const int lane = tid & 63, wid = tid >> 6;
    const int wm = wid & 3, wn = wid >> 2;
    const int l15 = lane & 15, lhi = lane >> 4;

    __syncthreads();

    for (int ks = 0; ks < 8; ++ks) {
        if (tid < 256) {  // A stage: 256 rows x 1 word, LUT unpack
            int row = tid;
            uint32_t w = s1p[((size_t)slot * 1024 + mt * 256 + row) * 8 + ks];
            #pragma unroll
            for (int bb = 0; bb < 4; ++bb) {
                int by = (w >> (bb * 8)) & 255;
                *(short8v*)&A[row][bb * 8] = *(const short8v*)&LUT[by][0];
            }
        }
        {   // B stage: 128 rows x 32 (hi and lo)
            int n = tid >> 2, ch = tid & 3;
            size_t wofs = ((size_t)e * 1024 + nt * 128 + n) * 256 + ks * 32 + ch * 8;
            *(short8v*)&Bh[n][ch * 8] = *(const short8v*)(w1bf + wofs);
            *(short8v*)&Bl[n][ch * 8] = *(const short8v*)(w1lo + wofs);
        }
        __syncthreads();
        {
            short8v af[4], bh[4], bl[4];
            int kofs = lhi * 8;
            #pragma unroll
            for (int mf = 0; mf < 4; ++mf) af[mf] = *(const short8v*)&A[wm * 64 + mf * 16 + l15][kofs];
            #pragma unroll
            for (int nf = 0; nf < 4; ++nf) {
                bh[nf] = *(const short8v*)&Bh[wn * 64 + nf * 16 + l15][kofs];
                bl[nf] = *(const short8v*)&Bl[wn * 64 + nf * 16 + l15][kofs];
            }
            #pragma unroll
            for (int mf = 0; mf < 4; ++mf)
                #pragma unroll
                for (int nf = 0; nf < 4; ++nf) {
                    acc[mf][nf] = __builtin_amdgcn_mfma_f32_16x16x32_bf16(af[mf], bh[nf], acc[mf][nf], 0, 0, 0);
                    acc[mf][nf] = __builtin_amdgcn_mfma_f32_16x16x32_bf16(af[mf], bl[nf], acc[mf][nf], 0, 0, 0);
                }
        }
        __syncthreads();
    }

    // epilogue: BN1 + LIF2 (4 timesteps live in the 4 acc regs of each lane) + ballot-pack
    const float tau = 1.5f + e * (2.5f / 7.0f);
    #pragma unroll
    for (int mf = 0; mf < 4; ++mf) {
        #pragma unroll
        for (int nf = 0; nf < 4; ++nf) {
            int o = nt * 128 + wn * 64 + nf * 16 + l15;
            float sc = sc1[e * 1024 + o], sh = sh1[e * 1024 + o];
            float v = 0.f;
            #pragma unroll
            for (int t = 0; t < 4; ++t) {
                float bnv = sc * acc[mf][nf][t] + sh;
                v = v + (bnv - v) / tau;
                bool s = (v >= 1.f);
                unsigned long long bal = __ballot(s);
                if (s) v = 0.f;
                if (l15 == 0) {
                    SPK[wm * 64 + mf * 16 + lhi * 4 + t][wn * 4 + nf] =
                        (unsigned short)((bal >> (lhi * 16)) & 0xFFFFull);
                }
            }
        }
    }
    __syncthreads();
    if (tid < 256) {
        int row = tid;
        u32x4 wv;
        #pragma unroll
        for (int k = 0; k < 4; ++k)
            wv[k] = (uint32_t)SPK[row][2 * k] | ((uint32_t)SPK[row][2 * k + 1] << 16);
        *(u32x4*)&s2p[((size_t)slot * 1024 + mt * 256 + row) * 32 + nt * 4] = wv;
    }
}

// ---------------- GEMM2 (spikes2 x w2) + BN2 + weighted combine with x ----------------
// block: M=256 rows, N=64 c, K=1024 in 16 steps of 64. 256 thr = 4 waves (4m x 1n).
// RANK 0: out = x + w*y ; RANK 1: out += w*y  (separate launches -> no races)
template <int RANK>
__global__ __launch_bounds__(256) void k_g2(const uint32_t* __restrict__ s2p,
                                            const short* __restrict__ w2bf,
                                            const float* __restrict__ sc2, const float* __restrict__ sh2,
                                            const int* __restrict__ slotE, const float* __restrict__ slotW,
                                            const float* __restrict__ x, float* __restrict__ out) {
    __shared__ __align__(16) char smem[50176];
    short (*A)[72]      = (short(*)[72])smem;                    // 256x72x2 = 36864
    short (*Bt)[72]     = (short(*)[72])(smem + 36864);          // 64x72x2  = 9216
    short (*LUT)[8]     = (short(*)[8])(smem + 36864 + 9216);    // 4096
    float (*Y)[32][65]  = (float(*)[32][65])smem;                // 33280, reused after K loop

    const int tid = threadIdx.x;
    const int b = blockIdx.x, mt = blockIdx.y, nt = blockIdx.z;
    const int slot = b * 2 + RANK;
    const int e = slotE[slot];
    const float wgt = slotW[slot];

    {
        short8v v;
        #pragma unroll
        for (int j = 0; j < 8; ++j) v[j] = ((tid >> j) & 1) ? (short)0x3F80 : (short)0;
        *(short8v*)&LUT[tid][0] = v;
    }

    f32x4 acc[4][4];
    #pragma unroll
    for (int i = 0; i < 4; ++i)
        #pragma unroll
        for (int j = 0; j < 4; ++j) acc[i][j] = (f32x4){0.f, 0.f, 0.f, 0.f};

    const int lane = tid & 63, wm = tid >> 6;
    const int l15 = lane & 15, lhi = lane >> 4;

    __syncthreads();

    for (int ks = 0; ks < 16; ++ks) {
        {   // A stage: each thread one row, 2 words -> 64 k
            int row = tid;
            u32x2 wv = *(const u32x2*)&s2p[((size_t)slot * 1024 + mt * 256 + row) * 32 + ks * 2];
            #pragma unroll
            for (int wi = 0; wi < 2; ++wi) {
                uint32_t w = wv[wi];
                #pragma unroll
                for (int bb = 0; bb < 4; ++bb) {
                    int by = (w >> (bb * 8)) & 255;
                    *(short8v*)&A[row][wi * 32 + bb * 8] = *(const short8v*)&LUT[by][0];
                }
            }
        }
        #pragma unroll
        for (int it = 0; it < 2; ++it) {  // B stage: 64 rows x 64 k
            int cid = tid + it * 256;
            int n = cid >> 3, ch = cid & 7;
            const short* src = w2bf + ((size_t)e * 256 + nt * 64 + n) * 1024 + ks * 64 + ch * 8;
            *(short8v*)&Bt[n][ch * 8] = *(const short8v*)src;
        }
        __syncthreads();
        #pragma unroll
        for (int kf = 0; kf < 2; ++kf) {
            short8v af[4], bf[4];
            int kofs = kf * 32 + lhi * 8;
            #pragma unroll
            for (int mf = 0; mf < 4; ++mf) af[mf] = *(const short8v*)&A[wm * 64 + mf * 16 + l15][kofs];
            #pragma unroll
            for (int nf = 0; nf < 4; ++nf) bf[nf] = *(const short8v*)&Bt[nf * 16 + l15][kofs];
            #pragma unroll
            for (int mf = 0; mf < 4; ++mf)
                #pragma unroll
                for (int nf = 0; nf < 4; ++nf)
                    acc[mf][nf] = __builtin_amdgcn_mfma_f32_16x16x32_bf16(af[mf], bf[nf], acc[mf][nf], 0, 0, 0);
        }
        __syncthreads();
    }

    // epilogue: BN2 + weight, LDS transpose in 2 chunks for coalesced out RMW
    #pragma unroll
    for (int ch2 = 0; ch2 < 2; ++ch2) {
        if ((wm >> 1) == ch2) {
            #pragma unroll
            for (int mf = 0; mf < 4; ++mf) {
                #pragma unroll
                for (int nf = 0; nf < 4; ++nf) {
                    int cl = nf * 16 + l15;
                    int cg = nt * 64 + cl;
                    float sc = sc2[e * 256 + cg], sh = sh2[e * 256 + cg];
                    int hwl = (wm & 1) * 16 + mf * 4 + lhi;
                    #pragma unroll
                    for (int t = 0; t < 4; ++t)
                        Y[t][hwl][cl] = wgt * (sc * acc[mf][nf][t] + sh);
                }
            }
        }
        __syncthreads();
        #pragma unroll
        for (int it = 0; it < 32; ++it) {
            int p = it * 8 + (tid >> 5);
            int t = p & 3, cl = p >> 2;
            int hwi = tid & 31;
            float val = Y[t][hwi][cl];
            int hwg = mt * 64 + ch2 * 32 + hwi;
            int cg = nt * 64 + cl;
            size_t oidx = (((size_t)t * 16 + b) * 256 + cg) * 256 + hwg;
            float base = (RANK == 0) ? x[oidx] : out[oidx];
            out[oidx] = base + val;
        }
        __syncthreads();
    }
}

extern "C" void kernel_launch(void* const* d_in, const int* in_sizes, int n_in,
                              void* d_out, int out_size, void* d_ws, size_t ws_size,
                              hipStream_t stream) {
    const float* x   = (const float*)d_in[0];
    const float* rw  = (const float*)d_in[1];
    const float* rb  = (const float*)d_in[2];
    const float* rg  = (const float*)d_in[3];
    const float* rbt = (const float*)d_in[4];
    const float* rm  = (const float*)d_in[5];
    const float* rv  = (const float*)d_in[6];
    const float* w1  = (const float*)d_in[7];
    const float* b1  = (const float*)d_in[8];
    const float* g1  = (const float*)d_in[9];
    const float* be1 = (const float*)d_in[10];
    const float* m1  = (const float*)d_in[11];
    const float* v1  = (const float*)d_in[12];
    const float* w2  = (const float*)d_in[13];
    const float* b2  = (const float*)d_in[14];
    const float* g2  = (const float*)d_in[15];
    const float* be2 = (const float*)d_in[16];
    const float* m2  = (const float*)d_in[17];
    const float* v2  = (const float*)d_in[18];
    float* out = (float*)d_out;

    char* ws = (char*)d_ws;
    short*    w1bf  = (short*)(ws);                   // 4 MiB
    short*    w1lo  = (short*)(ws + 4194304);         // 4 MiB
    short*    w2bf  = (short*)(ws + 8388608);         // 4 MiB
    float*    sc1   = (float*)(ws + 12582912);        // 32 KiB
    float*    sh1   = (float*)(ws + 12615680);        // 32 KiB
    float*    sc2   = (float*)(ws + 12648448);        // 8 KiB
    float*    sh2   = (float*)(ws + 12656640);        // 8 KiB
    float*    xbar  = (float*)(ws + 12664832);        // 16 KiB
    int*      slotE = (int*)  (ws + 12681216);        // 128 B
    float*    slotW = (float*)(ws + 12681344);        // 128 B
    uint32_t* s1p   = (uint32_t*)(ws + 12681728);     // 1 MiB
    uint32_t* s2p   = (uint32_t*)(ws + 13730304);     // 4 MiB  (total ~17.1 MiB)

    k_w  <<<8192, 256, 0, stream>>>(w1, w2, w1bf, w1lo, w2bf);
    k_bn <<<32, 256, 0, stream>>>(b1, g1, be1, m1, v1, b2, g2, be2, m2, v2, sc1, sh1, sc2, sh2);
    k_r1 <<<4096, 64, 0, stream>>>(x, xbar);
    k_r2 <<<1, 128, 0, stream>>>(xbar, rw, rb, rg, rbt, rm, rv, slotE, slotW);
    k_lif1<<<dim3(32, 8), 256, 0, stream>>>(x, slotE, s1p);
    k_g1 <<<dim3(32, 4, 8), 512, 0, stream>>>(s1p, w1bf, w1lo, sc1, sh1, slotE, s2p);
    k_g2<0><<<dim3(16, 4, 4), 256, 0, stream>>>(s2p, w2bf, sc2, sh2, slotE, slotW, x, out);
    k_g2<1><<<dim3(16, 4, 4), 256, 0, stream>>>(s2p, w2bf, sc2, sh2, slotE, slotW, x, out);
}

// Round 2
// 153.138 us; speedup vs baseline: 1.1231x; 1.1231x over previous
//
#include <hip/hip_runtime.h>
#include <hip/hip_bf16.h>
#include <stdint.h>

#define EPSF 1e-5f

typedef short    short8v __attribute__((ext_vector_type(8)));
typedef float    f32x4   __attribute__((ext_vector_type(4)));
typedef uint32_t u32x2   __attribute__((ext_vector_type(2)));
typedef uint32_t u32x4   __attribute__((ext_vector_type(4)));

// dims: T=4, B=16, C=256, H*W=256, Hid=1024, E=8, TOPK=2 -> 32 slots
// x layout (T,B,C,H,W): idx = ((t*16+b)*256+c)*256 + hw ; t-stride = 1048576

static __device__ __forceinline__ short bf16bits(float f) {
    __hip_bfloat16 h = __float2bfloat16(f);
    return *reinterpret_cast<short*>(&h);
}

// unpack 8 spike bits -> 8 bf16 (0.0 / 1.0) entirely in registers
static __device__ __forceinline__ short8v unpack8(uint32_t by) {
    uint32_t lo = ((by & 0xFu) * 0x00204081u) & 0x01010101u;   // bits0..3 -> bytes (0/1)
    uint32_t hi = ((by >> 4)   * 0x00204081u) & 0x01010101u;   // bits4..7
    union { short8v s; uint32_t u[4]; } r;
    // perm(0, src, sel): sel 0-3 = src bytes, sel 4 = byte0 of 0 (zero)
    r.u[0] = __builtin_amdgcn_perm(0u, lo, 0x04010400u) * 0x3F80u;  // [bit0,bit1]
    r.u[1] = __builtin_amdgcn_perm(0u, lo, 0x04030402u) * 0x3F80u;  // [bit2,bit3]
    r.u[2] = __builtin_amdgcn_perm(0u, hi, 0x04010400u) * 0x3F80u;  // [bit4,bit5]
    r.u[3] = __builtin_amdgcn_perm(0u, hi, 0x04030402u) * 0x3F80u;  // [bit6,bit7]
    return r.s;
}

typedef const __attribute__((address_space(1))) char* gas_p;
typedef __attribute__((address_space(3))) char* las_p;
static __device__ __forceinline__ void gl16(const void* g, void* l) {
    __builtin_amdgcn_global_load_lds((gas_p)g, (las_p)l, 16, 0, 0);
}

// ---------------- prep: weight convert+tile, BN fold, router stage-1 ----------------
// w1 tiled: w1t[e][nt=8][ks=8][n=128][40 shorts] (cols 32..39 pad), hi and lo arrays
// w2 tiled: w2t[e][nt=4][ks=16][n=64][72 shorts] (cols 64..71 pad)
__global__ void k_prep(const float* __restrict__ w1, const float* __restrict__ w2,
                       const float* __restrict__ x,
                       const float* __restrict__ b1, const float* __restrict__ g1, const float* __restrict__ be1,
                       const float* __restrict__ m1, const float* __restrict__ v1,
                       const float* __restrict__ b2, const float* __restrict__ g2, const float* __restrict__ be2,
                       const float* __restrict__ m2, const float* __restrict__ v2,
                       short* __restrict__ w1th, short* __restrict__ w1tl, short* __restrict__ w2t,
                       float* __restrict__ sc1, float* __restrict__ sh1,
                       float* __restrict__ sc2, float* __restrict__ sh2,
                       float* __restrict__ xbar) {
    int blk = blockIdx.x;
    if (blk < 8192) {
        int idx = blk * 256 + threadIdx.x;
        {   // w1 hi/lo split, tiled
            float f = w1[idx];
            __hip_bfloat16 h = __float2bfloat16(f);
            short hb = *reinterpret_cast<short*>(&h);
            float hf = __bfloat162float(h);
            int e = idx >> 18, o = (idx >> 8) & 1023, c = idx & 255;
            size_t off = ((((size_t)e * 8 + (o >> 7)) * 8 + (c >> 5)) * 128 + (o & 127)) * 40 + (c & 31);
            w1th[off] = hb;
            w1tl[off] = bf16bits(f - hf);
        }
        {   // w2 bf16, tiled
            float f = w2[idx];
            int e = idx >> 18, co = (idx >> 10) & 255, k = idx & 1023;
            size_t off = ((((size_t)e * 4 + (co >> 6)) * 16 + (k >> 6)) * 64 + (co & 63)) * 72 + (k & 63);
            w2t[off] = bf16bits(f);
        }
    } else if (blk < 8224) {
        int idx = (blk - 8192) * 256 + threadIdx.x;   // 0..8191
        {
            float s = g1[idx] / sqrtf(v1[idx] + EPSF);
            sc1[idx] = s;
            sh1[idx] = be1[idx] + s * (b1[idx] - m1[idx]);
        }
        if (idx < 2048) {
            float s = g2[idx] / sqrtf(v2[idx] + EPSF);
            sc2[idx] = s;
            sh2[idx] = be2[idx] + s * (b2[idx] - m2[idx]);
        }
    } else {
        // router stage 1: xbar[b*256+c] = mean over (T,H,W); 4 waves/block, 1 bc each
        int wid = threadIdx.x >> 6, lane = threadIdx.x & 63;
        int bc = (blk - 8224) * 4 + wid;
        const float* xp = x + (size_t)bc * 256;
        float s = 0.f;
        #pragma unroll
        for (int t = 0; t < 4; ++t)
            #pragma unroll
            for (int i = 0; i < 4; ++i)
                s += xp[(size_t)t * 1048576 + i * 64 + lane];
        #pragma unroll
        for (int off = 32; off; off >>= 1) s += __shfl_down(s, off);
        if (lane == 0) xbar[bc] = s * (1.0f / 1024.0f);
    }
}

// ---------------- router stage 2: logits -> top-2 -> expert-sorted 32 slots ----------------
__global__ void k_r2(const float* __restrict__ xbar, const float* __restrict__ rw, const float* __restrict__ rb,
                     const float* __restrict__ rg, const float* __restrict__ rbt,
                     const float* __restrict__ rm, const float* __restrict__ rv,
                     int* __restrict__ slotE, float* __restrict__ slotW, int* __restrict__ bslot) {
    __shared__ float L[16][8];
    __shared__ int   tE[32];
    __shared__ float tW[32];
    int tid = threadIdx.x; // 128
    if (tid < 128) {
        int b = tid >> 3, e = tid & 7;
        float s = 0.f;
        for (int c = 0; c < 256; ++c) s += xbar[b * 256 + c] * rw[e * 256 + c];
        s += rb[e];
        L[b][e] = rg[e] * (s - rm[e]) / sqrtf(rv[e] + EPSF) + rbt[e];
    }
    __syncthreads();
    if (tid < 16) {
        int b = tid;
        float l[8];
        #pragma unroll
        for (int e = 0; e < 8; ++e) l[e] = L[b][e];
        int i1 = 0;
        for (int e = 1; e < 8; ++e) if (l[e] > l[i1]) i1 = e;
        int i2 = (i1 == 0) ? 1 : 0;
        for (int e = 0; e < 8; ++e) { if (e == i1) continue; if (l[e] > l[i2]) i2 = e; }
        float d = l[i2] - l[i1];           // <= 0
        float ed = expf(d);
        tE[b * 2]     = i1; tW[b * 2]     = 1.f / (1.f + ed);
        tE[b * 2 + 1] = i2; tW[b * 2 + 1] = ed / (1.f + ed);
    }
    __syncthreads();
    if (tid == 0) {
        // stable counting sort by expert -> consecutive slots share expert (L2 locality)
        int pos = 0;
        for (int e = 0; e < 8; ++e)
            for (int i = 0; i < 32; ++i)
                if (tE[i] == e) {
                    slotE[pos] = e; slotW[pos] = tW[i]; bslot[i] = pos; ++pos;
                }
    }
}

// ---------------- LIF1: x -> packed spikes for BOTH slots of b in one pass ----------------
__global__ void k_lif1(const float* __restrict__ x, const int* __restrict__ slotE,
                       const int* __restrict__ bslot, uint32_t* __restrict__ s1p) {
    int b = blockIdx.x, wq = blockIdx.y;
    int s0 = bslot[b * 2], s1 = bslot[b * 2 + 1];
    float ta = 1.5f + slotE[s0] * (2.5f / 7.0f);
    float tb = 1.5f + slotE[s1] * (2.5f / 7.0f);
    int hw = threadIdx.x; // 256
    uint32_t wa[4] = {0, 0, 0, 0}, wb[4] = {0, 0, 0, 0};
    const float* xb = x + ((size_t)b * 256) * 256 + hw;
    for (int j = 0; j < 32; ++j) {
        const float* xp = xb + (size_t)(wq * 32 + j) * 256;
        float x0 = xp[0], x1 = xp[1048576], x2 = xp[2097152], x3 = xp[3145728];
        float v;
        v = x0 / ta;            if (v >= 1.f) { wa[0] |= 1u << j; v = 0.f; }
        v = v + (x1 - v) / ta;  if (v >= 1.f) { wa[1] |= 1u << j; v = 0.f; }
        v = v + (x2 - v) / ta;  if (v >= 1.f) { wa[2] |= 1u << j; v = 0.f; }
        v = v + (x3 - v) / ta;  if (v >= 1.f) { wa[3] |= 1u << j; }
        v = x0 / tb;            if (v >= 1.f) { wb[0] |= 1u << j; v = 0.f; }
        v = v + (x1 - v) / tb;  if (v >= 1.f) { wb[1] |= 1u << j; v = 0.f; }
        v = v + (x2 - v) / tb;  if (v >= 1.f) { wb[2] |= 1u << j; v = 0.f; }
        v = v + (x3 - v) / tb;  if (v >= 1.f) { wb[3] |= 1u << j; }
    }
    #pragma unroll
    for (int t = 0; t < 4; ++t) {
        s1p[((size_t)s0 * 1024 + hw * 4 + t) * 8 + wq] = wa[t];
        s1p[((size_t)s1 * 1024 + hw * 4 + t) * 8 + wq] = wb[t];
    }
}

// stage one 128x40-short tile (10240B = 640 x 16B) via global_load_lds, 512 threads
static __device__ __forceinline__ void stage_g1(const short* src, short* dst, int tid) {
    int wid = tid >> 6, lane = tid & 63;
    const char* g = (const char*)src;
    char* l = (char*)dst;
    gl16(g + (wid * 64 + lane) * 16, l + wid * 1024);
    if (wid < 2) gl16(g + (512 + wid * 64 + lane) * 16, l + 8192 + wid * 1024);
}

// ---------------- GEMM1 (reg-unpacked spikes x tiled w1 hi/lo) + BN1 + LIF2 -> s2p ----------------
// block: M=256 (64 tok x 4 t), N=128, 16 phases (8 ksteps x {hi,lo}). 512 thr = 8 waves (4m x 2n).
__global__ __launch_bounds__(512, 4) void k_g1(const uint32_t* __restrict__ s1p,
                                               const short* __restrict__ w1th, const short* __restrict__ w1tl,
                                               const float* __restrict__ sc1, const float* __restrict__ sh1,
                                               const int* __restrict__ slotE, uint32_t* __restrict__ s2p) {
    __shared__ __align__(16) short B[2][5120];
    __shared__ unsigned short SPK[256][8];

    const int tid = threadIdx.x;
    const int wg = ((blockIdx.x & 7) << 7) | (blockIdx.x >> 3);   // XCD swizzle: 128 blocks/XCD, nt uniform per XCD
    const int slot = wg & 31, mt = (wg >> 5) & 3, nt = wg >> 7;
    const int e = slotE[slot];
    const int lane = tid & 63, wid = tid >> 6;
    const int wm = wid & 3, wn = wid >> 2;
    const int l15 = lane & 15, lhi = lane >> 4;

    const int gbase = slot * 1024 + mt * 256 + wm * 64 + l15;

    f32x4 acc[4][4];
    #pragma unroll
    for (int i = 0; i < 4; ++i)
        #pragma unroll
        for (int j = 0; j < 4; ++j) acc[i][j] = (f32x4){0.f, 0.f, 0.f, 0.f};

    uint32_t wAc[4], wAn[4];
    #pragma unroll
    for (int mf = 0; mf < 4; ++mf) wAc[mf] = s1p[(size_t)(gbase + mf * 16) * 8];
    stage_g1(w1th + ((size_t)(e * 8 + nt) * 8) * 5120, &B[0][0], tid);
    __syncthreads();

    short8v af[4];
    #pragma unroll
    for (int s = 0; s < 16; ++s) {
        const int cur = s & 1, ks = s >> 1;
        if (cur == 0) {
            #pragma unroll
            for (int mf = 0; mf < 4; ++mf) af[mf] = unpack8((wAc[mf] >> (lhi * 8)) & 0xffu);
            if (ks < 7) {
                #pragma unroll
                for (int mf = 0; mf < 4; ++mf) wAn[mf] = s1p[(size_t)(gbase + mf * 16) * 8 + ks + 1];
            }
        }
        if (s < 15) {
            const short* base = ((s + 1) & 1) ? w1tl : w1th;
            stage_g1(base + ((size_t)(e * 8 + nt) * 8 + ((s + 1) >> 1)) * 5120, &B[cur ^ 1][0], tid);
        }
        short8v bf4[4];
        #pragma unroll
        for (int nf = 0; nf < 4; ++nf)
            bf4[nf] = *(const short8v*)&B[cur][(wn * 64 + nf * 16 + l15) * 40 + lhi * 8];
        #pragma unroll
        for (int mf = 0; mf < 4; ++mf)
            #pragma unroll
            for (int nf = 0; nf < 4; ++nf)
                acc[mf][nf] = __builtin_amdgcn_mfma_f32_16x16x32_bf16(af[mf], bf4[nf], acc[mf][nf], 0, 0, 0);
        if (cur == 1 && ks < 7) {
            #pragma unroll
            for (int mf = 0; mf < 4; ++mf) wAc[mf] = wAn[mf];
        }
        __syncthreads();
    }

    // epilogue: BN1 + LIF2 (4 timesteps live in each lane's 4 acc regs) + ballot-pack
    const float tau = 1.5f + e * (2.5f / 7.0f);
    #pragma unroll
    for (int mf = 0; mf < 4; ++mf) {
        #pragma unroll
        for (int nf = 0; nf < 4; ++nf) {
            int o = nt * 128 + wn * 64 + nf * 16 + l15;
            float sc = sc1[e * 1024 + o], sh = sh1[e * 1024 + o];
            float v = 0.f;
            #pragma unroll
            for (int t = 0; t < 4; ++t) {
                float bnv = sc * acc[mf][nf][t] + sh;
                v = v + (bnv - v) / tau;
                bool sp = (v >= 1.f);
                unsigned long long bal = __ballot(sp);
                if (sp) v = 0.f;
                if (l15 == 0) {
                    SPK[wm * 64 + mf * 16 + lhi * 4 + t][wn * 4 + nf] =
                        (unsigned short)((bal >> (lhi * 16)) & 0xFFFFull);
                }
            }
        }
    }
    __syncthreads();
    if (tid < 256) {
        int row = tid;
        u32x4 wv;
        #pragma unroll
        for (int k = 0; k < 4; ++k)
            wv[k] = (uint32_t)SPK[row][2 * k] | ((uint32_t)SPK[row][2 * k + 1] << 16);
        *(u32x4*)&s2p[((size_t)slot * 1024 + mt * 256 + row) * 32 + nt * 4] = wv;
    }
}

// stage one 64x72-short tile (9216B = 576 x 16B) via global_load_lds, 512 threads
static __device__ __forceinline__ void stage_g2(const short* src, char* dst, int tid) {
    int wid = tid >> 6, lane = tid & 63;
    const char* g = (const char*)src;
    gl16(g + (wid * 64 + lane) * 16, dst + wid * 1024);
    if (wid == 0) gl16(g + (512 + lane) * 16, dst + 8192);
}

// ---------------- GEMM2 both ranks fused (8 waves: 0-3 rank0, 4-7 rank1) + BN2 + combine ----------------
__global__ __launch_bounds__(512, 2) void k_g2(const uint32_t* __restrict__ s2p,
                                               const short* __restrict__ w2t,
                                               const float* __restrict__ sc2, const float* __restrict__ sh2,
                                               const int* __restrict__ slotE, const float* __restrict__ slotW,
                                               const int* __restrict__ bslot,
                                               const float* __restrict__ x, float* __restrict__ out) {
    __shared__ __align__(16) char smem[36864];
    short (*Bt)[4608] = (short(*)[4608])smem;      // [cur*2 + rank]

    const int tid = threadIdx.x;
    const int wg = ((blockIdx.x & 7) << 5) | (blockIdx.x >> 3);   // XCD swizzle
    const int b = wg & 15, mt = (wg >> 4) & 3, nt = wg >> 6;
    const int lane = tid & 63, wid = tid >> 6;
    const int rank = wid >> 2, wm = wid & 3;
    const int l15 = lane & 15, lhi = lane >> 4;

    const int slot = bslot[b * 2 + rank];
    const int e = slotE[slot];
    const float wgt = slotW[slot];
    const int e0 = slotE[bslot[b * 2]], e1 = slotE[bslot[b * 2 + 1]];

    const int gbase = slot * 1024 + mt * 256 + wm * 64 + l15;

    f32x4 acc[4][4];
    #pragma unroll
    for (int i = 0; i < 4; ++i)
        #pragma unroll
        for (int j = 0; j < 4; ++j) acc[i][j] = (f32x4){0.f, 0.f, 0.f, 0.f};

    u32x2 wc[4], wn2[4];
    #pragma unroll
    for (int mf = 0; mf < 4; ++mf) wc[mf] = *(const u32x2*)&s2p[(size_t)(gbase + mf * 16) * 32];
    stage_g2(w2t + ((size_t)(e0 * 4 + nt) * 16) * 4608, (char*)&Bt[0][0], tid);
    stage_g2(w2t + ((size_t)(e1 * 4 + nt) * 16) * 4608, (char*)&Bt[1][0], tid);
    __syncthreads();

    #pragma unroll
    for (int ks = 0; ks < 16; ++ks) {
        const int cur = ks & 1;
        if (ks < 15) {
            stage_g2(w2t + ((size_t)(e0 * 4 + nt) * 16 + ks + 1) * 4608, (char*)&Bt[(cur ^ 1) * 2][0], tid);
            stage_g2(w2t + ((size_t)(e1 * 4 + nt) * 16 + ks + 1) * 4608, (char*)&Bt[(cur ^ 1) * 2 + 1][0], tid);
            #pragma unroll
            for (int mf = 0; mf < 4; ++mf)
                wn2[mf] = *(const u32x2*)&s2p[(size_t)(gbase + mf * 16) * 32 + (ks + 1) * 2];
        }
        #pragma unroll
        for (int kf = 0; kf < 2; ++kf) {
            short8v af2[4], bf2[4];
            #pragma unroll
            for (int mf = 0; mf < 4; ++mf) af2[mf] = unpack8((wc[mf][kf] >> (lhi * 8)) & 0xffu);
            #pragma unroll
            for (int nf = 0; nf < 4; ++nf)
                bf2[nf] = *(const short8v*)&Bt[cur * 2 + rank][(nf * 16 + l15) * 72 + kf * 32 + lhi * 8];
            #pragma unroll
            for (int mf = 0; mf < 4; ++mf)
                #pragma unroll
                for (int nf = 0; nf < 4; ++nf)
                    acc[mf][nf] = __builtin_amdgcn_mfma_f32_16x16x32_bf16(af2[mf], bf2[nf], acc[mf][nf], 0, 0, 0);
        }
        if (ks < 15) {
            #pragma unroll
            for (int mf = 0; mf < 4; ++mf) wc[mf] = wn2[mf];
        }
        __syncthreads();
    }

    // epilogue: rank1 writes wgt*y1 to LDS Y, rank0 adds wgt*y0, then stream out = x + Y
    float (*Y)[32][65] = (float(*)[32][65])smem;
    #pragma unroll
    for (int ch2 = 0; ch2 < 2; ++ch2) {
        if (rank == 1 && (wm >> 1) == ch2) {
            #pragma unroll
            for (int mf = 0; mf < 4; ++mf)
                #pragma unroll
                for (int nf = 0; nf < 4; ++nf) {
                    int cl = nf * 16 + l15;
                    int cg = nt * 64 + cl;
                    float sc = sc2[e * 256 + cg], sh = sh2[e * 256 + cg];
                    int hwl = (wm & 1) * 16 + mf * 4 + lhi;
                    #pragma unroll
                    for (int t = 0; t < 4; ++t)
                        Y[t][hwl][cl] = wgt * (sc * acc[mf][nf][t] + sh);
                }
        }
        __syncthreads();
        if (rank == 0 && (wm >> 1) == ch2) {
            #pragma unroll
            for (int mf = 0; mf < 4; ++mf)
                #pragma unroll
                for (int nf = 0; nf < 4; ++nf) {
                    int cl = nf * 16 + l15;
                    int cg = nt * 64 + cl;
                    float sc = sc2[e * 256 + cg], sh = sh2[e * 256 + cg];
                    int hwl = (wm & 1) * 16 + mf * 4 + lhi;
                    #pragma unroll
                    for (int t = 0; t < 4; ++t)
                        Y[t][hwl][cl] += wgt * (sc * acc[mf][nf][t] + sh);
                }
        }
        __syncthreads();
        #pragma unroll
        for (int it = 0; it < 16; ++it) {
            int f2 = it * 512 + tid;
            int hwi = f2 & 31, rest = f2 >> 5;
            int t = rest & 3, cl = rest >> 2;
            size_t oidx = (((size_t)t * 16 + b) * 256 + (nt * 64 + cl)) * 256 + (mt * 64 + ch2 * 32 + hwi);
            out[oidx] = x[oidx] + Y[t][hwi][cl];
        }
        __syncthreads();
    }
}

extern "C" void kernel_launch(void* const* d_in, const int* in_sizes, int n_in,
                              void* d_out, int out_size, void* d_ws, size_t ws_size,
                              hipStream_t stream) {
    const float* x   = (const float*)d_in[0];
    const float* rw  = (const float*)d_in[1];
    const float* rb  = (const float*)d_in[2];
    const float* rg  = (const float*)d_in[3];
    const float* rbt = (const float*)d_in[4];
    const float* rm  = (const float*)d_in[5];
    const float* rv  = (const float*)d_in[6];
    const float* w1  = (const float*)d_in[7];
    const float* b1  = (const float*)d_in[8];
    const float* g1  = (const float*)d_in[9];
    const float* be1 = (const float*)d_in[10];
    const float* m1  = (const float*)d_in[11];
    const float* v1  = (const float*)d_in[12];
    const float* w2  = (const float*)d_in[13];
    const float* b2  = (const float*)d_in[14];
    const float* g2  = (const float*)d_in[15];
    const float* be2 = (const float*)d_in[16];
    const float* m2  = (const float*)d_in[17];
    const float* v2  = (const float*)d_in[18];
    float* out = (float*)d_out;

    char* ws = (char*)d_ws;
    short*    w1th  = (short*)(ws);                    // 5,242,880 B
    short*    w1tl  = (short*)(ws + 5242880);          // 5,242,880 B
    short*    w2t   = (short*)(ws + 10485760);         // 4,718,592 B
    float*    sc1   = (float*)(ws + 15204352);         // 32 KiB
    float*    sh1   = (float*)(ws + 15237120);         // 32 KiB
    float*    sc2   = (float*)(ws + 15269888);         // 8 KiB
    float*    sh2   = (float*)(ws + 15278080);         // 8 KiB
    float*    xbar  = (float*)(ws + 15286272);         // 16 KiB
    int*      slotE = (int*)  (ws + 15302656);         // 128 B
    float*    slotW = (float*)(ws + 15302784);         // 128 B
    int*      bslot = (int*)  (ws + 15302912);         // 128 B
    uint32_t* s1p   = (uint32_t*)(ws + 15303040);      // 1 MiB
    uint32_t* s2p   = (uint32_t*)(ws + 16351616);      // 4 MiB  (total ~20.5 MiB)

    k_prep<<<9248, 256, 0, stream>>>(w1, w2, x, b1, g1, be1, m1, v1, b2, g2, be2, m2, v2,
                                     w1th, w1tl, w2t, sc1, sh1, sc2, sh2, xbar);
    k_r2  <<<1, 128, 0, stream>>>(xbar, rw, rb, rg, rbt, rm, rv, slotE, slotW, bslot);
    k_lif1<<<dim3(16, 8), 256, 0, stream>>>(x, slotE, bslot, s1p);
    k_g1  <<<1024, 512, 0, stream>>>(s1p, w1th, w1tl, sc1, sh1, slotE, s2p);
    k_g2  <<<256, 512, 0, stream>>>(s2p, w2t, sc2, sh2, slotE, slotW, bslot, x, out);
}

// Round 3
// 128.270 us; speedup vs baseline: 1.3408x; 1.1939x over previous
//
#include <hip/hip_runtime.h>
#include <hip/hip_bf16.h>
#include <stdint.h>

#define EPSF 1e-5f

typedef short    short8v __attribute__((ext_vector_type(8)));
typedef float    f32x4   __attribute__((ext_vector_type(4)));
typedef uint32_t u32x2   __attribute__((ext_vector_type(2)));
typedef uint32_t u32x4   __attribute__((ext_vector_type(4)));

// dims: T=4, B=16, C=256, H*W=256, Hid=1024, E=8, TOPK=2 -> 32 slots
// x layout (T,B,C,H,W): idx = ((t*16+b)*256+c)*256 + hw ; t-stride = 1048576

static __device__ __forceinline__ short bf16bits(float f) {
    __hip_bfloat16 h = __float2bfloat16(f);
    return *reinterpret_cast<short*>(&h);
}

// unpack 8 spike bits -> 8 bf16 (0.0 / 1.0) entirely in registers
static __device__ __forceinline__ short8v unpack8(uint32_t by) {
    uint32_t lo = ((by & 0xFu) * 0x00204081u) & 0x01010101u;
    uint32_t hi = ((by >> 4)   * 0x00204081u) & 0x01010101u;
    union { short8v s; uint32_t u[4]; } r;
    r.u[0] = __builtin_amdgcn_perm(0u, lo, 0x04010400u) * 0x3F80u;
    r.u[1] = __builtin_amdgcn_perm(0u, lo, 0x04030402u) * 0x3F80u;
    r.u[2] = __builtin_amdgcn_perm(0u, hi, 0x04010400u) * 0x3F80u;
    r.u[3] = __builtin_amdgcn_perm(0u, hi, 0x04030402u) * 0x3F80u;
    return r.s;
}

typedef const __attribute__((address_space(1))) char* gas_p;
typedef __attribute__((address_space(3))) char* las_p;
static __device__ __forceinline__ void gl16(const void* g, void* l) {
    // lds dst is wave-uniform base; HW adds lane*16
    __builtin_amdgcn_global_load_lds((gas_p)g, (las_p)l, 16, 0, 0);
}
#define SBAR()  __builtin_amdgcn_s_barrier()
#define SCHED0() __builtin_amdgcn_sched_barrier(0)

// ---------------- prep: weight convert+tile(+swizzle), BN fold, router stage-1 ----------------
// w1c[e][nt8][ks8][h2][n128][u4][j8] shorts; u = (cl>>3) ^ ((n>>1)&3)   (8 MiB)
// w2t[e][nt4][ks16][n64][u8][j8] shorts;   u = (kl>>3) ^ (n&7)          (4 MiB)
__global__ void k_prep(const float* __restrict__ w1, const float* __restrict__ w2,
                       const float* __restrict__ x,
                       const float* __restrict__ b1, const float* __restrict__ g1, const float* __restrict__ be1,
                       const float* __restrict__ m1, const float* __restrict__ v1,
                       const float* __restrict__ b2, const float* __restrict__ g2, const float* __restrict__ be2,
                       const float* __restrict__ m2, const float* __restrict__ v2,
                       short* __restrict__ w1c, short* __restrict__ w2t,
                       float* __restrict__ sc1, float* __restrict__ sh1,
                       float* __restrict__ sc2, float* __restrict__ sh2,
                       float* __restrict__ xbar) {
    int blk = blockIdx.x;
    if (blk < 8192) {
        int idx = blk * 256 + threadIdx.x;
        {   // w1 hi/lo split, tiled+swizzled
            float f = w1[idx];
            __hip_bfloat16 h = __float2bfloat16(f);
            short hb = *reinterpret_cast<short*>(&h);
            float hf = __bfloat162float(h);
            int e = idx >> 18, o = (idx >> 8) & 1023, c = idx & 255;
            int nt = o >> 7, n = o & 127, ks = c >> 5, cl = c & 31;
            int u = (cl >> 3) ^ ((n >> 1) & 3), j = cl & 7;
            size_t base = (((size_t)((e * 8 + nt) * 8 + ks) * 2) * 128 + n) * 32 + u * 8 + j;
            w1c[base] = hb;                      // hi
            w1c[base + 4096] = bf16bits(f - hf); // lo
        }
        {   // w2 bf16, tiled+swizzled
            float f = w2[idx];
            int e = idx >> 18, co = (idx >> 10) & 255, k = idx & 1023;
            int nt = co >> 6, n = co & 63, ks = k >> 6, kl = k & 63;
            int u = (kl >> 3) ^ (n & 7), j = kl & 7;
            size_t off = (((size_t)((e * 4 + nt) * 16 + ks) * 64) + n) * 64 + u * 8 + j;
            w2t[off] = bf16bits(f);
        }
    } else if (blk < 8224) {
        int idx = (blk - 8192) * 256 + threadIdx.x;   // 0..8191
        {
            float s = g1[idx] / sqrtf(v1[idx] + EPSF);
            sc1[idx] = s;
            sh1[idx] = be1[idx] + s * (b1[idx] - m1[idx]);
        }
        if (idx < 2048) {
            float s = g2[idx] / sqrtf(v2[idx] + EPSF);
            sc2[idx] = s;
            sh2[idx] = be2[idx] + s * (b2[idx] - m2[idx]);
        }
    } else {
        int wid = threadIdx.x >> 6, lane = threadIdx.x & 63;
        int bc = (blk - 8224) * 4 + wid;
        const float* xp = x + (size_t)bc * 256;
        float s = 0.f;
        #pragma unroll
        for (int t = 0; t < 4; ++t)
            #pragma unroll
            for (int i = 0; i < 4; ++i)
                s += xp[(size_t)t * 1048576 + i * 64 + lane];
        #pragma unroll
        for (int off = 32; off; off >>= 1) s += __shfl_down(s, off);
        if (lane == 0) xbar[bc] = s * (1.0f / 1024.0f);
    }
}

// ---------------- router stage 2: logits -> top-2 -> expert-sorted 32 slots ----------------
__global__ void k_r2(const float* __restrict__ xbar, const float* __restrict__ rw, const float* __restrict__ rb,
                     const float* __restrict__ rg, const float* __restrict__ rbt,
                     const float* __restrict__ rm, const float* __restrict__ rv,
                     int* __restrict__ slotE, float* __restrict__ slotW, int* __restrict__ bslot) {
    __shared__ float L[16][8];
    __shared__ int   tE[32];
    __shared__ float tW[32];
    int tid = threadIdx.x; // 128
    if (tid < 128) {
        int b = tid >> 3, e = tid & 7;
        float s = 0.f;
        for (int c = 0; c < 256; ++c) s += xbar[b * 256 + c] * rw[e * 256 + c];
        s += rb[e];
        L[b][e] = rg[e] * (s - rm[e]) / sqrtf(rv[e] + EPSF) + rbt[e];
    }
    __syncthreads();
    if (tid < 16) {
        int b = tid;
        float l[8];
        #pragma unroll
        for (int e = 0; e < 8; ++e) l[e] = L[b][e];
        int i1 = 0;
        for (int e = 1; e < 8; ++e) if (l[e] > l[i1]) i1 = e;
        int i2 = (i1 == 0) ? 1 : 0;
        for (int e = 0; e < 8; ++e) { if (e == i1) continue; if (l[e] > l[i2]) i2 = e; }
        float d = l[i2] - l[i1];
        float ed = expf(d);
        tE[b * 2]     = i1; tW[b * 2]     = 1.f / (1.f + ed);
        tE[b * 2 + 1] = i2; tW[b * 2 + 1] = ed / (1.f + ed);
    }
    __syncthreads();
    if (tid == 0) {
        int pos = 0;
        for (int e = 0; e < 8; ++e)
            for (int i = 0; i < 32; ++i)
                if (tE[i] == e) {
                    slotE[pos] = e; slotW[pos] = tW[i]; bslot[i] = pos; ++pos;
                }
    }
}

// ---------------- LIF1: x -> packed spikes for BOTH slots of b; s1p[slot][row=hw*4+t][8 words] ----------------
__global__ void k_lif1(const float* __restrict__ x, const int* __restrict__ slotE,
                       const int* __restrict__ bslot, uint32_t* __restrict__ s1p) {
    int b = blockIdx.x, wq = blockIdx.y;
    int s0 = bslot[b * 2], s1 = bslot[b * 2 + 1];
    float ta = 1.5f + slotE[s0] * (2.5f / 7.0f);
    float tb = 1.5f + slotE[s1] * (2.5f / 7.0f);
    int hw = threadIdx.x; // 256
    uint32_t wa[4] = {0, 0, 0, 0}, wb[4] = {0, 0, 0, 0};
    const float* xb = x + ((size_t)b * 256) * 256 + hw;
    for (int j = 0; j < 32; ++j) {
        const float* xp = xb + (size_t)(wq * 32 + j) * 256;
        float x0 = xp[0], x1 = xp[1048576], x2 = xp[2097152], x3 = xp[3145728];
        float v;
        v = x0 / ta;            if (v >= 1.f) { wa[0] |= 1u << j; v = 0.f; }
        v = v + (x1 - v) / ta;  if (v >= 1.f) { wa[1] |= 1u << j; v = 0.f; }
        v = v + (x2 - v) / ta;  if (v >= 1.f) { wa[2] |= 1u << j; v = 0.f; }
        v = v + (x3 - v) / ta;  if (v >= 1.f) { wa[3] |= 1u << j; }
        v = x0 / tb;            if (v >= 1.f) { wb[0] |= 1u << j; v = 0.f; }
        v = v + (x1 - v) / tb;  if (v >= 1.f) { wb[1] |= 1u << j; v = 0.f; }
        v = v + (x2 - v) / tb;  if (v >= 1.f) { wb[2] |= 1u << j; v = 0.f; }
        v = v + (x3 - v) / tb;  if (v >= 1.f) { wb[3] |= 1u << j; }
    }
    #pragma unroll
    for (int t = 0; t < 4; ++t) {
        s1p[((size_t)s0 * 1024 + hw * 4 + t) * 8 + wq] = wa[t];
        s1p[((size_t)s1 * 1024 + hw * 4 + t) * 8 + wq] = wb[t];
    }
}

// ================= GEMM1: spikes x w1(hi/lo) + BN1 + LIF2 -> s2p =================
// M=256 (64 hw x 4 t), N=128, 8 phases of K=32x{hi,lo}. 512 thr = 8 waves (4m x 2n).
// LDS: A 8KB | 3 x 16KB B-buffers. 3-deep counted-vmcnt pipeline.
__global__ __launch_bounds__(512, 2) void k_g1(const uint32_t* __restrict__ s1p,
                                               const short* __restrict__ w1c,
                                               const float* __restrict__ sc1, const float* __restrict__ sh1,
                                               const int* __restrict__ slotE, uint32_t* __restrict__ s2p) {
    __shared__ __align__(16) char SM[57344];   // A:0..8191 | bufs: 8192 + cur*16384

    const int tid = threadIdx.x;
    const int wg = ((blockIdx.x & 7) << 7) | (blockIdx.x >> 3);   // XCD swizzle: nt uniform per XCD
    const int slot = wg & 31, mt = (wg >> 5) & 3, nt = wg >> 7;
    const int e = slotE[slot];
    const int lane = tid & 63, wid = tid >> 6;
    const int wm = wid & 3, wn = wid >> 2;
    const int l15 = lane & 15, lhi = lane >> 4;

    f32x4 acc[4][4];
    #pragma unroll
    for (int i = 0; i < 4; ++i)
        #pragma unroll
        for (int j = 0; j < 4; ++j) acc[i][j] = (f32x4){0.f, 0.f, 0.f, 0.f};

    const short* wbase = w1c + (size_t)(e * 8 + nt) * 8 * 8192;   // 8 tiles of 16KB (shorts: 8192/tile)
    const char*  abase = (const char*)(s1p + (size_t)(slot * 1024 + mt * 256) * 8);

    // prologue: stage A (1/thread), then B ksteps 0,1,2 (2/thread each) -> 7 outstanding
    gl16(abase + tid * 16, SM + wid * 1024);
    SCHED0();
    #pragma unroll
    for (int p = 0; p < 3; ++p) {
        const char* g = (const char*)(wbase + p * 8192);
        char* dst = SM + 8192 + p * 16384;
        gl16(g + tid * 16, dst + wid * 1024);
        gl16(g + (512 + tid) * 16, dst + 8192 + wid * 1024);
        SCHED0();
    }

    const uint32_t* Al = (const uint32_t*)SM;

    #pragma unroll
    for (int ks = 0; ks < 8; ++ks) {
        const int cur = ks % 3;
        if (ks < 6)      asm volatile("s_waitcnt vmcnt(4)");
        else if (ks == 6) asm volatile("s_waitcnt vmcnt(2)");
        else              asm volatile("s_waitcnt vmcnt(0)");
        SBAR();
        SCHED0();
        const short* Bb = (const short*)(SM + 8192 + cur * 16384);
        short8v bh[4], bl[4];
        uint32_t aw[4];
        #pragma unroll
        for (int nf = 0; nf < 4; ++nf) {
            int n = wn * 64 + nf * 16 + l15;
            int sw = (lhi ^ ((n >> 1) & 3)) << 3;
            bh[nf] = *(const short8v*)&Bb[n * 32 + sw];
            bl[nf] = *(const short8v*)&Bb[4096 + n * 32 + sw];
        }
        #pragma unroll
        for (int mf = 0; mf < 4; ++mf)
            aw[mf] = Al[(wm * 64 + mf * 16 + l15) * 8 + ks];
        asm volatile("s_waitcnt lgkmcnt(0)");
        SCHED0();
        SBAR();                                  // all waves done reading buf cur
        if (ks < 5) {                            // stage ks+3 into (just-freed) cur
            const char* g = (const char*)(wbase + (ks + 3) * 8192);
            char* dst = SM + 8192 + cur * 16384;
            gl16(g + tid * 16, dst + wid * 1024);
            gl16(g + (512 + tid) * 16, dst + 8192 + wid * 1024);
        }
        SCHED0();
        __builtin_amdgcn_s_setprio(1);
        #pragma unroll
        for (int mf = 0; mf < 4; ++mf) {
            short8v af = unpack8((aw[mf] >> (lhi * 8)) & 0xffu);
            #pragma unroll
            for (int nf = 0; nf < 4; ++nf)
                acc[mf][nf] = __builtin_amdgcn_mfma_f32_16x16x32_bf16(af, bh[nf], acc[mf][nf], 0, 0, 0);
            #pragma unroll
            for (int nf = 0; nf < 4; ++nf)
                acc[mf][nf] = __builtin_amdgcn_mfma_f32_16x16x32_bf16(af, bl[nf], acc[mf][nf], 0, 0, 0);
        }
        __builtin_amdgcn_s_setprio(0);
    }

    __syncthreads();
    // epilogue: BN1 + LIF2 + ballot-pack (SPK aliases A region)
    unsigned short (*SPK)[8] = (unsigned short(*)[8])SM;
    const float tau = 1.5f + e * (2.5f / 7.0f);
    #pragma unroll
    for (int mf = 0; mf < 4; ++mf) {
        #pragma unroll
        for (int nf = 0; nf < 4; ++nf) {
            int o = nt * 128 + wn * 64 + nf * 16 + l15;
            float sc = sc1[e * 1024 + o], sh = sh1[e * 1024 + o];
            float v = 0.f;
            #pragma unroll
            for (int t = 0; t < 4; ++t) {
                float bnv = sc * acc[mf][nf][t] + sh;
                v = v + (bnv - v) / tau;
                bool sp = (v >= 1.f);
                unsigned long long bal = __ballot(sp);
                if (sp) v = 0.f;
                if (l15 == 0)
                    SPK[wm * 64 + mf * 16 + lhi * 4 + t][wn * 4 + nf] =
                        (unsigned short)((bal >> (lhi * 16)) & 0xFFFFull);
            }
        }
    }
    __syncthreads();
    if (tid < 256) {
        int row = tid;
        u32x4 wv;
        #pragma unroll
        for (int k = 0; k < 4; ++k)
            wv[k] = (uint32_t)SPK[row][2 * k] | ((uint32_t)SPK[row][2 * k + 1] << 16);
        // s2p layout: [slot][nt][row1024][4 words] -> contiguous coalesced block store
        *(u32x4*)&s2p[((size_t)(slot * 8 + nt) * 1024 + mt * 256 + row) * 4] = wv;
    }
}

// ================= GEMM2: spikes2 x w2, both ranks fused, + BN2 + combine =================
// M=256, N=64, 16 phases of K=64. 512 thr = 8 waves (rank = wid>>2, wm = wid&3).
// LDS: 3 x 16KB B-buffers (8KB per rank). A via double-buffered per-lane global loads.
__global__ __launch_bounds__(512, 2) void k_g2(const uint32_t* __restrict__ s2p,
                                               const short* __restrict__ w2t,
                                               const float* __restrict__ sc2, const float* __restrict__ sh2,
                                               const int* __restrict__ slotE, const float* __restrict__ slotW,
                                               const int* __restrict__ bslot,
                                               const float* __restrict__ x, float* __restrict__ out) {
    __shared__ __align__(16) char SM[49152];

    const int tid = threadIdx.x;
    const int wg = ((blockIdx.x & 7) << 5) | (blockIdx.x >> 3);   // XCD swizzle
    const int b = wg & 15, mt = (wg >> 4) & 3, nt = wg >> 6;
    const int lane = tid & 63, wid = tid >> 6;
    const int rank = wid >> 2, wm = wid & 3;
    const int l15 = lane & 15, lhi = lane >> 4;

    const int slot = bslot[b * 2 + rank];
    const int e = slotE[slot];
    const float wgt = slotW[slot];
    const int e0 = slotE[bslot[b * 2]], e1 = slotE[bslot[b * 2 + 1]];

    f32x4 acc[4][4];
    #pragma unroll
    for (int i = 0; i < 4; ++i)
        #pragma unroll
        for (int j = 0; j < 4; ++j) acc[i][j] = (f32x4){0.f, 0.f, 0.f, 0.f};

    const short* w0 = w2t + (size_t)(e0 * 4 + nt) * 16 * 4096;
    const short* w1b = w2t + (size_t)(e1 * 4 + nt) * 16 * 4096;
    // per-lane A base: word index = ((slot*8 + (ks>>1))*1024 + mt*256 + r)*4 + (ks&1)*2
    const uint32_t* abase[4];
    #pragma unroll
    for (int mf = 0; mf < 4; ++mf)
        abase[mf] = s2p + ((size_t)slot * 8192 + mt * 256 + wm * 64 + mf * 16 + l15) * 4;

    u32x2 awp[2][4];
    // prologue issue order: A0, A1, s0, s1, s2  (counted: 4+4+2+2+2)
    #pragma unroll
    for (int mf = 0; mf < 4; ++mf) awp[0][mf] = *(const u32x2*)(abase[mf]);
    SCHED0();
    #pragma unroll
    for (int mf = 0; mf < 4; ++mf) awp[1][mf] = *(const u32x2*)(abase[mf] + 4096 + 2);
    SCHED0();
    #pragma unroll
    for (int p = 0; p < 3; ++p) {
        char* dst = SM + p * 16384;
        gl16((const char*)(w0 + p * 4096) + tid * 16, dst + wid * 1024);
        gl16((const char*)(w1b + p * 4096) + tid * 16, dst + 8192 + wid * 1024);
        SCHED0();
    }

    #pragma unroll
    for (int ks = 0; ks < 16; ++ks) {
        const int cur = ks % 3;
        if (ks == 0)       asm volatile("s_waitcnt vmcnt(4)");
        else if (ks < 14)  asm volatile("s_waitcnt vmcnt(8)");
        else if (ks == 14) asm volatile("s_waitcnt vmcnt(6)");
        else               asm volatile("s_waitcnt vmcnt(0)");
        SBAR();
        SCHED0();
        const short* Bb = (const short*)(SM + cur * 16384 + rank * 8192);
        short8v bq[2][4];
        #pragma unroll
        for (int kf = 0; kf < 2; ++kf)
            #pragma unroll
            for (int nf = 0; nf < 4; ++nf) {
                int n = nf * 16 + l15;
                bq[kf][nf] = *(const short8v*)&Bb[n * 64 + (((kf * 4 + lhi) ^ (n & 7)) << 3)];
            }
        u32x2 wloc[4];
        #pragma unroll
        for (int mf = 0; mf < 4; ++mf) wloc[mf] = awp[ks & 1][mf];
        asm volatile("s_waitcnt lgkmcnt(0)");
        SCHED0();
        SBAR();                                  // all waves done reading buf cur
        if (ks + 2 < 16) {                       // A(ks+2) -> awp[ks&1]
            #pragma unroll
            for (int mf = 0; mf < 4; ++mf)
                awp[ks & 1][mf] = *(const u32x2*)(abase[mf] + ((ks + 2) >> 1) * 4096 + ((ks + 2) & 1) * 2);
        }
        SCHED0();
        if (ks + 3 < 16) {                       // stage B(ks+3) into cur
            char* dst = SM + cur * 16384;
            gl16((const char*)(w0 + (ks + 3) * 4096) + tid * 16, dst + wid * 1024);
            gl16((const char*)(w1b + (ks + 3) * 4096) + tid * 16, dst + 8192 + wid * 1024);
        }
        SCHED0();
        __builtin_amdgcn_s_setprio(1);
        #pragma unroll
        for (int mf = 0; mf < 4; ++mf) {
            #pragma unroll
            for (int kf = 0; kf < 2; ++kf) {
                short8v af = unpack8((wloc[mf][kf] >> (lhi * 8)) & 0xffu);
                #pragma unroll
                for (int nf = 0; nf < 4; ++nf)
                    acc[mf][nf] = __builtin_amdgcn_mfma_f32_16x16x32_bf16(af, bq[kf][nf], acc[mf][nf], 0, 0, 0);
            }
        }
        __builtin_amdgcn_s_setprio(0);
    }

    // epilogue: rank1 writes wgt*y to LDS Y, rank0 adds, stream out = x + Y
    float (*Y)[32][65] = (float(*)[32][65])SM;
    #pragma unroll
    for (int ch2 = 0; ch2 < 2; ++ch2) {
        if (rank == 1 && (wm >> 1) == ch2) {
            #pragma unroll
            for (int mf = 0; mf < 4; ++mf)
                #pragma unroll
                for (int nf = 0; nf < 4; ++nf) {
                    int cl = nf * 16 + l15;
                    int cg = nt * 64 + cl;
                    float sc = sc2[e * 256 + cg], sh = sh2[e * 256 + cg];
                    int hwl = (wm & 1) * 16 + mf * 4 + lhi;
                    #pragma unroll
                    for (int t = 0; t < 4; ++t)
                        Y[t][hwl][cl] = wgt * (sc * acc[mf][nf][t] + sh);
                }
        }
        __syncthreads();
        if (rank == 0 && (wm >> 1) == ch2) {
            #pragma unroll
            for (int mf = 0; mf < 4; ++mf)
                #pragma unroll
                for (int nf = 0; nf < 4; ++nf) {
                    int cl = nf * 16 + l15;
                    int cg = nt * 64 + cl;
                    float sc = sc2[e * 256 + cg], sh = sh2[e * 256 + cg];
                    int hwl = (wm & 1) * 16 + mf * 4 + lhi;
                    #pragma unroll
                    for (int t = 0; t < 4; ++t)
                        Y[t][hwl][cl] += wgt * (sc * acc[mf][nf][t] + sh);
                }
        }
        __syncthreads();
        #pragma unroll
        for (int it = 0; it < 16; ++it) {
            int f2 = it * 512 + tid;
            int hwi = f2 & 31, rest = f2 >> 5;
            int t = rest & 3, cl = rest >> 2;
            size_t oidx = (((size_t)t * 16 + b) * 256 + (nt * 64 + cl)) * 256 + (mt * 64 + ch2 * 32 + hwi);
            out[oidx] = x[oidx] + Y[t][hwi][cl];
        }
        __syncthreads();
    }
}

extern "C" void kernel_launch(void* const* d_in, const int* in_sizes, int n_in,
                              void* d_out, int out_size, void* d_ws, size_t ws_size,
                              hipStream_t stream) {
    const float* x   = (const float*)d_in[0];
    const float* rw  = (const float*)d_in[1];
    const float* rb  = (const float*)d_in[2];
    const float* rg  = (const float*)d_in[3];
    const float* rbt = (const float*)d_in[4];
    const float* rm  = (const float*)d_in[5];
    const float* rv  = (const float*)d_in[6];
    const float* w1  = (const float*)d_in[7];
    const float* b1  = (const float*)d_in[8];
    const float* g1  = (const float*)d_in[9];
    const float* be1 = (const float*)d_in[10];
    const float* m1  = (const float*)d_in[11];
    const float* v1  = (const float*)d_in[12];
    const float* w2  = (const float*)d_in[13];
    const float* b2  = (const float*)d_in[14];
    const float* g2  = (const float*)d_in[15];
    const float* be2 = (const float*)d_in[16];
    const float* m2  = (const float*)d_in[17];
    const float* v2  = (const float*)d_in[18];
    float* out = (float*)d_out;

    char* ws = (char*)d_ws;
    short*    w1c   = (short*)(ws);                    // 8 MiB
    short*    w2t   = (short*)(ws + 8388608);          // 4 MiB
    float*    sc1   = (float*)(ws + 12582912);         // 32 KiB
    float*    sh1   = (float*)(ws + 12615680);         // 32 KiB
    float*    sc2   = (float*)(ws + 12648448);         // 8 KiB
    float*    sh2   = (float*)(ws + 12656640);         // 8 KiB
    float*    xbar  = (float*)(ws + 12664832);         // 16 KiB
    int*      slotE = (int*)  (ws + 12681216);         // 128 B
    float*    slotW = (float*)(ws + 12681344);         // 128 B
    int*      bslot = (int*)  (ws + 12681472);         // 128 B
    uint32_t* s1p   = (uint32_t*)(ws + 12681728);      // 1 MiB
    uint32_t* s2p   = (uint32_t*)(ws + 13730304);      // 4 MiB  (total ~17.1 MiB)

    k_prep<<<9248, 256, 0, stream>>>(w1, w2, x, b1, g1, be1, m1, v1, b2, g2, be2, m2, v2,
                                     w1c, w2t, sc1, sh1, sc2, sh2, xbar);
    k_r2  <<<1, 128, 0, stream>>>(xbar, rw, rb, rg, rbt, rm, rv, slotE, slotW, bslot);
    k_lif1<<<dim3(16, 8), 256, 0, stream>>>(x, slotE, bslot, s1p);
    k_g1  <<<1024, 512, 0, stream>>>(s1p, w1c, sc1, sh1, slotE, s2p);
    k_g2  <<<256, 512, 0, stream>>>(s2p, w2t, sc2, sh2, slotE, slotW, bslot, x, out);
}